// Round 3
// baseline (190.436 us; speedup 1.0000x reference)
//
#include <hip/hip_runtime.h>
#include <hip/hip_fp16.h>

// Composite loss: 0.16*MSE + 0.84*(1-SSIM), 16x3x512x512 f32, win=11 sigma=1.5
// Vertical-first streaming design, fp16 intermediate planes:
//   block = full image width (512 cols) x OH=4 output rows
//   phase A: per-thread 2-col vertical conv of 5 planes (registers) -> LDS fp16
//   phase B: 64 groups x 8 cols x 1 row/thread, aligned b128 LDS reads,
//            horizontal conv + SSIM map in fp32 registers
// LDS = 5*4*512*2 = 20480 B -> 8 blocks/CU by LDS; VGPR-capped at 6 waves/SIMD.

#define OH 4

__global__ __launch_bounds__(256, 6) void ssim_fused(
    const float* __restrict__ pred, const float* __restrict__ targ,
    float* __restrict__ accum)
{
    __shared__ __half sV[5 * OH * 512];   // 20480 B

    // Normalized 11-tap Gaussian (sigma=1.5)
    const float wv[11] = {
        0.00102838f, 0.00759876f, 0.03600078f, 0.10936070f, 0.21300554f,
        0.26601173f,
        0.21300554f, 0.10936070f, 0.03600078f, 0.00759876f, 0.00102838f };

    const int tid = threadIdx.x;
    // XCD-aware swizzle: 6144 blocks = 8 XCDs * 768 contiguous
    const int bid = ((int)blockIdx.x & 7) * 768 + ((int)blockIdx.x >> 3);
    const int img = bid >> 7;             // 48 planes
    const int oy0 = (bid & 127) * OH;     // 128 row-strips
    const float* __restrict__ P = pred + (size_t)img * (512 * 512);
    const float* __restrict__ T = targ + (size_t)img * (512 * 512);

    // ---------------- phase A: vertical 11-tap conv, 2 cols/thread ----------
    const int c0 = tid * 2;

    float acc[5][OH][2];
    #pragma unroll
    for (int p = 0; p < 5; ++p)
        #pragma unroll
        for (int j = 0; j < OH; ++j) { acc[p][j][0] = 0.f; acc[p][j][1] = 0.f; }

    float mse_acc = 0.f;

    #pragma unroll
    for (int i = 0; i < OH + 10; ++i) {
        int gy = oy0 + i; if (gy > 511) gy = 511;   // clamped rows feed only masked outputs
        const float2 xv = *reinterpret_cast<const float2*>(P + gy * 512 + c0);
        const float2 yv = *reinterpret_cast<const float2*>(T + gy * 512 + c0);
        const float x0 = fminf(fmaxf(xv.x, 0.f), 1.f);
        const float x1 = fminf(fmaxf(xv.y, 0.f), 1.f);
        const float y0 = fminf(fmaxf(yv.x, 0.f), 1.f);
        const float y1 = fminf(fmaxf(yv.y, 0.f), 1.f);
        if (i < OH) {   // this block's disjoint MSE rows
            const float d0 = x0 - y0, d1 = x1 - y1;
            mse_acc += d0 * d0 + d1 * d1;
        }
        const float pr0[5] = { x0, y0, x0 * x0, y0 * y0, x0 * y0 };
        const float pr1[5] = { x1, y1, x1 * x1, y1 * y1, x1 * y1 };
        #pragma unroll
        for (int j = 0; j < OH; ++j) {
            const int k = i - j;
            if (k >= 0 && k <= 10) {
                const float w = wv[k];
                #pragma unroll
                for (int p = 0; p < 5; ++p) {
                    acc[p][j][0] = fmaf(w, pr0[p], acc[p][j][0]);
                    acc[p][j][1] = fmaf(w, pr1[p], acc[p][j][1]);
                }
            }
        }
    }

    #pragma unroll
    for (int p = 0; p < 5; ++p)
        #pragma unroll
        for (int j = 0; j < OH; ++j)
            *reinterpret_cast<__half2*>(&sV[(p * OH + j) * 512 + c0]) =
                __floats2half2_rn(acc[p][j][0], acc[p][j][1]);

    __syncthreads();

    // ------- phase B: horizontal 11-tap conv + SSIM map (8 cols/thread) -----
    const int g   = tid & 63;         // 64 col-groups
    const int r   = tid >> 6;         // row 0..3
    const int oc0 = g * 8;
    // third aligned read, clamped in-bounds (values only feed masked cols)
    const int c2  = (oc0 + 16 <= 504) ? (oc0 + 16) : 504;

    float hc[5][8];
    #pragma unroll
    for (int p = 0; p < 5; ++p) {
        const __half* rowb = &sV[(p * OH + r) * 512];
        union { float4 f4; __half h[8]; } u0, u1, u2;
        u0.f4 = *reinterpret_cast<const float4*>(rowb + oc0);
        u1.f4 = *reinterpret_cast<const float4*>(rowb + oc0 + 8);
        u2.f4 = *reinterpret_cast<const float4*>(rowb + c2);
        float win[24];
        #pragma unroll
        for (int i = 0; i < 8; ++i) {
            win[i]      = __half2float(u0.h[i]);
            win[i + 8]  = __half2float(u1.h[i]);
            win[i + 16] = __half2float(u2.h[i]);
        }
        #pragma unroll
        for (int cc = 0; cc < 8; ++cc) {
            float s = 0.f;
            #pragma unroll
            for (int dx = 0; dx < 11; ++dx)
                s = fmaf(wv[dx], win[cc + dx], s);
            hc[p][cc] = s;
        }
    }

    float ssim_acc = 0.f;
    {
        const float C1 = 0.0001f, C2 = 0.0009f;
        const int oyg = oy0 + r;
        if (oyg < 502) {
            #pragma unroll
            for (int cc = 0; cc < 8; ++cc) {
                if (oc0 + cc < 502) {
                    const float mu1 = hc[0][cc], mu2 = hc[1][cc];
                    const float m11 = mu1 * mu1, m22 = mu2 * mu2, m12 = mu1 * mu2;
                    const float s1  = hc[2][cc] - m11;
                    const float s2  = hc[3][cc] - m22;
                    const float s12 = hc[4][cc] - m12;
                    const float num = (2.f * m12 + C1) * (2.f * s12 + C2);
                    const float den = (m11 + m22 + C1) * (s1 + s2 + C2);
                    ssim_acc += num * __builtin_amdgcn_rcpf(den);
                }
            }
        }
    }

    // ---------------- reduction: wave shfl -> LDS -> 2 atomics --------------
    float vx = mse_acc, vy = ssim_acc;
    #pragma unroll
    for (int off = 32; off > 0; off >>= 1) {
        vx += __shfl_down(vx, off);
        vy += __shfl_down(vy, off);
    }
    __syncthreads();                     // phase-B LDS reads done; reuse sV
    float* redf = reinterpret_cast<float*>(sV);
    const int wave = tid >> 6;
    if ((tid & 63) == 0) { redf[wave * 2] = vx; redf[wave * 2 + 1] = vy; }
    __syncthreads();
    if (tid == 0) {
        atomicAdd(&accum[0], redf[0] + redf[2] + redf[4] + redf[6]);
        atomicAdd(&accum[1], redf[1] + redf[3] + redf[5] + redf[7]);
    }
}

__global__ void ssim_finalize(const float* __restrict__ acc, float* __restrict__ out)
{
    // N_mse = 16*3*512*512 = 12582912 ; N_ssim = 16*3*502*502 = 12096192
    const float mse  = acc[0] * (1.0f / 12582912.0f);
    const float ssim = acc[1] * (1.0f / 12096192.0f);
    out[0] = 0.16f * mse + 0.84f * (1.0f - ssim);
}

extern "C" void kernel_launch(void* const* d_in, const int* in_sizes, int n_in,
                              void* d_out, int out_size, void* d_ws, size_t ws_size,
                              hipStream_t stream)
{
    const float* pred = (const float*)d_in[0];
    const float* targ = (const float*)d_in[1];
    float* ws = (float*)d_ws;

    hipMemsetAsync(ws, 0, 2 * sizeof(float), stream);
    // 48 planes * 128 row-strips = 6144 blocks
    ssim_fused<<<6144, 256, 0, stream>>>(pred, targ, ws);
    ssim_finalize<<<1, 1, 0, stream>>>(ws, (float*)d_out);
}

// Round 4
// 173.955 us; speedup vs baseline: 1.0947x; 1.0947x over previous
//
#include <hip/hip_runtime.h>
#include <hip/hip_fp16.h>

// Composite loss: 0.16*MSE + 0.84*(1-SSIM), 16x3x512x512 f32, win=11 sigma=1.5
// Vertical-first streaming, fp16 intermediate planes, BATCH-ISSUED global loads:
//   block = full image width (512 cols) x OH=4 output rows
//   phase A: pre-issue all 14 row-loads (float2, independent regs), then
//            vertical 11-tap conv of 5 planes -> LDS fp16
//   phase B: 64 groups x 8 cols x 1 row/thread, aligned b128 LDS reads,
//            horizontal conv + SSIM map in fp32 registers
// LDS = 20480 B; VGPR ~110 -> 4 waves/SIMD, load latency paid once per wave.

#define OH 4

__global__ __launch_bounds__(256, 4) void ssim_fused(
    const float* __restrict__ pred, const float* __restrict__ targ,
    float* __restrict__ accum)
{
    __shared__ __half sV[5 * OH * 512];   // 20480 B

    // Normalized 11-tap Gaussian (sigma=1.5)
    const float wv[11] = {
        0.00102838f, 0.00759876f, 0.03600078f, 0.10936070f, 0.21300554f,
        0.26601173f,
        0.21300554f, 0.10936070f, 0.03600078f, 0.00759876f, 0.00102838f };

    const int tid = threadIdx.x;
    // XCD-aware swizzle: 6144 blocks = 8 XCDs * 768 contiguous
    const int bid = ((int)blockIdx.x & 7) * 768 + ((int)blockIdx.x >> 3);
    const int img = bid >> 7;             // 48 planes
    const int oy0 = (bid & 127) * OH;     // 128 row-strips
    const float* __restrict__ P = pred + (size_t)img * (512 * 512);
    const float* __restrict__ T = targ + (size_t)img * (512 * 512);

    // ---------------- phase A: batch-issue 14 rows, then vertical conv ------
    const int c0 = tid * 2;

    float2 xr[OH + 10], yr[OH + 10];
    #pragma unroll
    for (int i = 0; i < OH + 10; ++i) {
        int gy = oy0 + i; if (gy > 511) gy = 511;   // clamped rows feed only masked outputs
        xr[i] = *reinterpret_cast<const float2*>(P + gy * 512 + c0);
        yr[i] = *reinterpret_cast<const float2*>(T + gy * 512 + c0);
    }

    float acc[5][OH][2];
    #pragma unroll
    for (int p = 0; p < 5; ++p)
        #pragma unroll
        for (int j = 0; j < OH; ++j) { acc[p][j][0] = 0.f; acc[p][j][1] = 0.f; }

    float mse_acc = 0.f;

    #pragma unroll
    for (int i = 0; i < OH + 10; ++i) {
        const float x0 = fminf(fmaxf(xr[i].x, 0.f), 1.f);
        const float x1 = fminf(fmaxf(xr[i].y, 0.f), 1.f);
        const float y0 = fminf(fmaxf(yr[i].x, 0.f), 1.f);
        const float y1 = fminf(fmaxf(yr[i].y, 0.f), 1.f);
        if (i < OH) {   // this block's disjoint MSE rows
            const float d0 = x0 - y0, d1 = x1 - y1;
            mse_acc += d0 * d0 + d1 * d1;
        }
        const float pr0[5] = { x0, y0, x0 * x0, y0 * y0, x0 * y0 };
        const float pr1[5] = { x1, y1, x1 * x1, y1 * y1, x1 * y1 };
        #pragma unroll
        for (int j = 0; j < OH; ++j) {
            const int k = i - j;
            if (k >= 0 && k <= 10) {
                const float w = wv[k];
                #pragma unroll
                for (int p = 0; p < 5; ++p) {
                    acc[p][j][0] = fmaf(w, pr0[p], acc[p][j][0]);
                    acc[p][j][1] = fmaf(w, pr1[p], acc[p][j][1]);
                }
            }
        }
    }

    #pragma unroll
    for (int p = 0; p < 5; ++p)
        #pragma unroll
        for (int j = 0; j < OH; ++j)
            *reinterpret_cast<__half2*>(&sV[(p * OH + j) * 512 + c0]) =
                __floats2half2_rn(acc[p][j][0], acc[p][j][1]);

    __syncthreads();

    // ------- phase B: horizontal 11-tap conv + SSIM map (8 cols/thread) -----
    const int g   = tid & 63;         // 64 col-groups
    const int r   = tid >> 6;         // row 0..3
    const int oc0 = g * 8;
    // third aligned read, clamped in-bounds (values only feed masked cols)
    const int c2  = (oc0 + 16 <= 504) ? (oc0 + 16) : 504;

    float hc[5][8];
    #pragma unroll
    for (int p = 0; p < 5; ++p) {
        const __half* rowb = &sV[(p * OH + r) * 512];
        union { float4 f4; __half h[8]; } u0, u1, u2;
        u0.f4 = *reinterpret_cast<const float4*>(rowb + oc0);
        u1.f4 = *reinterpret_cast<const float4*>(rowb + oc0 + 8);
        u2.f4 = *reinterpret_cast<const float4*>(rowb + c2);
        float win[24];
        #pragma unroll
        for (int i = 0; i < 8; ++i) {
            win[i]      = __half2float(u0.h[i]);
            win[i + 8]  = __half2float(u1.h[i]);
            win[i + 16] = __half2float(u2.h[i]);
        }
        #pragma unroll
        for (int cc = 0; cc < 8; ++cc) {
            float s = 0.f;
            #pragma unroll
            for (int dx = 0; dx < 11; ++dx)
                s = fmaf(wv[dx], win[cc + dx], s);
            hc[p][cc] = s;
        }
    }

    float ssim_acc = 0.f;
    {
        const float C1 = 0.0001f, C2 = 0.0009f;
        const int oyg = oy0 + r;
        if (oyg < 502) {
            #pragma unroll
            for (int cc = 0; cc < 8; ++cc) {
                if (oc0 + cc < 502) {
                    const float mu1 = hc[0][cc], mu2 = hc[1][cc];
                    const float m11 = mu1 * mu1, m22 = mu2 * mu2, m12 = mu1 * mu2;
                    const float s1  = hc[2][cc] - m11;
                    const float s2  = hc[3][cc] - m22;
                    const float s12 = hc[4][cc] - m12;
                    const float num = (2.f * m12 + C1) * (2.f * s12 + C2);
                    const float den = (m11 + m22 + C1) * (s1 + s2 + C2);
                    ssim_acc += num * __builtin_amdgcn_rcpf(den);
                }
            }
        }
    }

    // ---------------- reduction: wave shfl -> LDS -> 2 atomics --------------
    float vx = mse_acc, vy = ssim_acc;
    #pragma unroll
    for (int off = 32; off > 0; off >>= 1) {
        vx += __shfl_down(vx, off);
        vy += __shfl_down(vy, off);
    }
    __syncthreads();                     // phase-B LDS reads done; reuse sV
    float* redf = reinterpret_cast<float*>(sV);
    const int wave = tid >> 6;
    if ((tid & 63) == 0) { redf[wave * 2] = vx; redf[wave * 2 + 1] = vy; }
    __syncthreads();
    if (tid == 0) {
        atomicAdd(&accum[0], redf[0] + redf[2] + redf[4] + redf[6]);
        atomicAdd(&accum[1], redf[1] + redf[3] + redf[5] + redf[7]);
    }
}

__global__ void ssim_finalize(const float* __restrict__ acc, float* __restrict__ out)
{
    // N_mse = 16*3*512*512 = 12582912 ; N_ssim = 16*3*502*502 = 12096192
    const float mse  = acc[0] * (1.0f / 12582912.0f);
    const float ssim = acc[1] * (1.0f / 12096192.0f);
    out[0] = 0.16f * mse + 0.84f * (1.0f - ssim);
}

extern "C" void kernel_launch(void* const* d_in, const int* in_sizes, int n_in,
                              void* d_out, int out_size, void* d_ws, size_t ws_size,
                              hipStream_t stream)
{
    const float* pred = (const float*)d_in[0];
    const float* targ = (const float*)d_in[1];
    float* ws = (float*)d_ws;

    hipMemsetAsync(ws, 0, 2 * sizeof(float), stream);
    // 48 planes * 128 row-strips = 6144 blocks
    ssim_fused<<<6144, 256, 0, stream>>>(pred, targ, ws);
    ssim_finalize<<<1, 1, 0, stream>>>(ws, (float*)d_out);
}

// Round 5
// 173.560 us; speedup vs baseline: 1.0972x; 1.0023x over previous
//
#include <hip/hip_runtime.h>
#include <hip/hip_fp16.h>

// Composite loss: 0.16*MSE + 0.84*(1-SSIM), 16x3x512x512 f32, win=11 sigma=1.5
// Vertical-first streaming, fp16 intermediate planes, FORCED batch-issued loads:
//   block = full image width (512 cols) x OH=4 output rows
//   phase A: issue ALL 28 row-loads (float2) then sched_barrier(0) fence so
//            the compiler cannot sink them; consume in issue order (vmcnt
//            pipelining: one long wait for row 0, rest stream in)
//   phase B: 64 groups x 8 cols x 1 row/thread, aligned b128 LDS reads,
//            horizontal conv + SSIM map in fp32 registers
// LDS = 20480 B; VGPR ~120 -> 4 waves/SIMD.

#define OH 4

__global__ __launch_bounds__(256, 4) void ssim_fused(
    const float* __restrict__ pred, const float* __restrict__ targ,
    float* __restrict__ accum)
{
    __shared__ __half sV[5 * OH * 512];   // 20480 B

    // Normalized 11-tap Gaussian (sigma=1.5)
    const float wv[11] = {
        0.00102838f, 0.00759876f, 0.03600078f, 0.10936070f, 0.21300554f,
        0.26601173f,
        0.21300554f, 0.10936070f, 0.03600078f, 0.00759876f, 0.00102838f };

    const int tid = threadIdx.x;
    // XCD-aware swizzle: 6144 blocks = 8 XCDs * 768 contiguous
    const int bid = ((int)blockIdx.x & 7) * 768 + ((int)blockIdx.x >> 3);
    const int img = bid >> 7;             // 48 planes
    const int oy0 = (bid & 127) * OH;     // 128 row-strips
    const float* __restrict__ P = pred + (size_t)img * (512 * 512);
    const float* __restrict__ T = targ + (size_t)img * (512 * 512);

    // ---------------- phase A: batch-issue ALL 14 row-pairs -----------------
    const int c0 = tid * 2;

    float2 xr[OH + 10], yr[OH + 10];
    #pragma unroll
    for (int i = 0; i < OH + 10; ++i) {
        int gy = oy0 + i; if (gy > 511) gy = 511;   // clamped rows feed only masked outputs
        xr[i] = *reinterpret_cast<const float2*>(P + gy * 512 + c0);
        yr[i] = *reinterpret_cast<const float2*>(T + gy * 512 + c0);
    }
    __builtin_amdgcn_sched_barrier(0);   // fence: no load may sink past here

    float acc[5][OH][2];
    #pragma unroll
    for (int p = 0; p < 5; ++p)
        #pragma unroll
        for (int j = 0; j < OH; ++j) { acc[p][j][0] = 0.f; acc[p][j][1] = 0.f; }

    float mse_acc = 0.f;

    #pragma unroll
    for (int i = 0; i < OH + 10; ++i) {
        const float x0 = fminf(fmaxf(xr[i].x, 0.f), 1.f);
        const float x1 = fminf(fmaxf(xr[i].y, 0.f), 1.f);
        const float y0 = fminf(fmaxf(yr[i].x, 0.f), 1.f);
        const float y1 = fminf(fmaxf(yr[i].y, 0.f), 1.f);
        if (i < OH) {   // this block's disjoint MSE rows
            const float d0 = x0 - y0, d1 = x1 - y1;
            mse_acc += d0 * d0 + d1 * d1;
        }
        const float pr0[5] = { x0, y0, x0 * x0, y0 * y0, x0 * y0 };
        const float pr1[5] = { x1, y1, x1 * x1, y1 * y1, x1 * y1 };
        #pragma unroll
        for (int j = 0; j < OH; ++j) {
            const int k = i - j;
            if (k >= 0 && k <= 10) {
                const float w = wv[k];
                #pragma unroll
                for (int p = 0; p < 5; ++p) {
                    acc[p][j][0] = fmaf(w, pr0[p], acc[p][j][0]);
                    acc[p][j][1] = fmaf(w, pr1[p], acc[p][j][1]);
                }
            }
        }
    }

    #pragma unroll
    for (int p = 0; p < 5; ++p)
        #pragma unroll
        for (int j = 0; j < OH; ++j)
            *reinterpret_cast<__half2*>(&sV[(p * OH + j) * 512 + c0]) =
                __floats2half2_rn(acc[p][j][0], acc[p][j][1]);

    __syncthreads();

    // ------- phase B: horizontal 11-tap conv + SSIM map (8 cols/thread) -----
    const int g   = tid & 63;         // 64 col-groups
    const int r   = tid >> 6;         // row 0..3
    const int oc0 = g * 8;
    // third aligned read, clamped in-bounds (values only feed masked cols)
    const int c2  = (oc0 + 16 <= 504) ? (oc0 + 16) : 504;

    float hc[5][8];
    #pragma unroll
    for (int p = 0; p < 5; ++p) {
        const __half* rowb = &sV[(p * OH + r) * 512];
        union { float4 f4; __half h[8]; } u0, u1, u2;
        u0.f4 = *reinterpret_cast<const float4*>(rowb + oc0);
        u1.f4 = *reinterpret_cast<const float4*>(rowb + oc0 + 8);
        u2.f4 = *reinterpret_cast<const float4*>(rowb + c2);
        float win[24];
        #pragma unroll
        for (int i = 0; i < 8; ++i) {
            win[i]      = __half2float(u0.h[i]);
            win[i + 8]  = __half2float(u1.h[i]);
            win[i + 16] = __half2float(u2.h[i]);
        }
        #pragma unroll
        for (int cc = 0; cc < 8; ++cc) {
            float s = 0.f;
            #pragma unroll
            for (int dx = 0; dx < 11; ++dx)
                s = fmaf(wv[dx], win[cc + dx], s);
            hc[p][cc] = s;
        }
    }

    float ssim_acc = 0.f;
    {
        const float C1 = 0.0001f, C2 = 0.0009f;
        const int oyg = oy0 + r;
        if (oyg < 502) {
            #pragma unroll
            for (int cc = 0; cc < 8; ++cc) {
                if (oc0 + cc < 502) {
                    const float mu1 = hc[0][cc], mu2 = hc[1][cc];
                    const float m11 = mu1 * mu1, m22 = mu2 * mu2, m12 = mu1 * mu2;
                    const float s1  = hc[2][cc] - m11;
                    const float s2  = hc[3][cc] - m22;
                    const float s12 = hc[4][cc] - m12;
                    const float num = (2.f * m12 + C1) * (2.f * s12 + C2);
                    const float den = (m11 + m22 + C1) * (s1 + s2 + C2);
                    ssim_acc += num * __builtin_amdgcn_rcpf(den);
                }
            }
        }
    }

    // ---------------- reduction: wave shfl -> LDS -> 2 atomics --------------
    float vx = mse_acc, vy = ssim_acc;
    #pragma unroll
    for (int off = 32; off > 0; off >>= 1) {
        vx += __shfl_down(vx, off);
        vy += __shfl_down(vy, off);
    }
    __syncthreads();                     // phase-B LDS reads done; reuse sV
    float* redf = reinterpret_cast<float*>(sV);
    const int wave = tid >> 6;
    if ((tid & 63) == 0) { redf[wave * 2] = vx; redf[wave * 2 + 1] = vy; }
    __syncthreads();
    if (tid == 0) {
        atomicAdd(&accum[0], redf[0] + redf[2] + redf[4] + redf[6]);
        atomicAdd(&accum[1], redf[1] + redf[3] + redf[5] + redf[7]);
    }
}

__global__ void ssim_finalize(const float* __restrict__ acc, float* __restrict__ out)
{
    // N_mse = 16*3*512*512 = 12582912 ; N_ssim = 16*3*502*502 = 12096192
    const float mse  = acc[0] * (1.0f / 12582912.0f);
    const float ssim = acc[1] * (1.0f / 12096192.0f);
    out[0] = 0.16f * mse + 0.84f * (1.0f - ssim);
}

extern "C" void kernel_launch(void* const* d_in, const int* in_sizes, int n_in,
                              void* d_out, int out_size, void* d_ws, size_t ws_size,
                              hipStream_t stream)
{
    const float* pred = (const float*)d_in[0];
    const float* targ = (const float*)d_in[1];
    float* ws = (float*)d_ws;

    hipMemsetAsync(ws, 0, 2 * sizeof(float), stream);
    // 48 planes * 128 row-strips = 6144 blocks
    ssim_fused<<<6144, 256, 0, stream>>>(pred, targ, ws);
    ssim_finalize<<<1, 1, 0, stream>>>(ws, (float*)d_out);
}